// Round 18
// baseline (316.505 us; speedup 1.0000x reference)
//
#include <hip/hip_runtime.h>
#include <hip/hip_bf16.h>

typedef __attribute__((ext_vector_type(8))) short bf16x8;
typedef __attribute__((ext_vector_type(16))) float f32x16;
typedef __attribute__((ext_vector_type(4))) unsigned u32x4;

#define TH 0.01f
#define MFMA32(a, b, c) __builtin_amdgcn_mfma_f32_32x32x16_bf16(a, b, c, 0, 0, 0)

constexpr int D = 512, F = 2048, BM = 128, NC = 64;

// ---- fused-kernel LDS map (fallback path, verified R12/R17) ----
constexpr int W1A_O = 0;
constexpr int W1B_O = 32768;
constexpr int W2A_O = 65536;
constexpr int W2B_O = 98304;
constexpr int H2_0  = 131072;
constexpr int H2_1  = 139264;
constexpr int HP_O  = 147456;
constexpr int B1_O  = 155648;
constexpr int LDS_TOTAL = 163840;

static __device__ __forceinline__ short f2bf(float f) {
  union { float f; unsigned u; } v; v.f = f;
  unsigned r = v.u + 0x7FFFu + ((v.u >> 16) & 1u);  // RNE
  return (short)(r >> 16);
}

static __device__ __forceinline__ void gl16(const void* g, char* l) {
  __builtin_amdgcn_global_load_lds(
      (const __attribute__((address_space(1))) unsigned*)g,
      (__attribute__((address_space(3))) unsigned*)l, 16, 0, 0);
}

// ---------------------------------------------------------------------------
// Fragment-major staged weights (verified R12-R17, byte-identical):
// w1s: 64 regions (hcol-chunk c) x 32KB: granule g: ks=g>>6 (0..31), lane;
//      elems j: w1[ks*16 + (lane>>5)*8 + j][c*32 + (lane&31)]
// w2s: 64 regions (k-chunk c) x 32KB: granule g: ks=g>>10, cf=(g>>6)&15, lane;
//      elems j: w2[c*32 + ks*16 + (lane>>5)*8 + j][cf*32 + (lane&31)]
// ---------------------------------------------------------------------------
__global__ void prep_weights(const float* __restrict__ w1, const float* __restrict__ w2,
                             short* __restrict__ w1s, short* __restrict__ w2s) {
  int G = blockIdx.x * 256 + threadIdx.x;
  if (G < 131072) {
    int c = G >> 11, g = G & 2047;
    int ks = g >> 6, lane = g & 63, l31 = lane & 31, l5 = lane >> 5;
    bf16x8 v;
#pragma unroll
    for (int j = 0; j < 8; ++j)
      v[j] = f2bf(w1[(size_t)(ks * 16 + l5 * 8 + j) * F + c * 32 + l31]);
    *(bf16x8*)(w1s + (size_t)G * 8) = v;
  } else {
    int H = G - 131072;
    int c = H >> 11, g = H & 2047;
    int ks = g >> 10, cf = (g >> 6) & 15, lane = g & 63, l31 = lane & 31, l5 = lane >> 5;
    bf16x8 v;
#pragma unroll
    for (int j = 0; j < 8; ++j)
      v[j] = f2bf(w2[(size_t)(c * 32 + ks * 16 + l5 * 8 + j) * D + cf * 32 + l31]);
    *(bf16x8*)(w2s + (size_t)H * 8) = v;
  }
}

#define ISSUE4(loff, gptr)                                                      \
  do {                                                                          \
    _Pragma("unroll") for (int _t = 0; _t < 4; ++_t)                            \
        gl16((const char*)(gptr) + (size_t)(_t * 512 + tid) * 16,               \
             smem + (loff) + (_t * 512 + tid) * 16);                            \
  } while (0)

#define ISSUE1(loff, gptr)                                                      \
  gl16((const char*)(gptr) + (size_t)tid * 16, smem + (loff) + (size_t)tid * 16)

// ===========================================================================
// UNFUSED PATH, kernel 1: h = relu(x*w1 + b1), h staged to global (bf16).
// h layout: region (row>>7, hk>>5) of 8KB; within: [rt_local=(row>>5)&3]
//   [bp=hk_local>>3 (0..3)][row&31][16B = 8 bf16 hks bp*8..+7].
// grid = (M/256)*2: blockIdx -> rowblk=bid>>1 (256 rows), fh=bid&1 (1024 hks).
// LDS: w1 slot0 0..32KB, slot1 32..64KB, x slab 64..128KB.
// ===========================================================================
__global__ __launch_bounds__(512, 2)
void g1_kernel(const float* __restrict__ x, const float* __restrict__ b1,
               const char* __restrict__ w1g, char* __restrict__ hg,
               unsigned* __restrict__ spikeg) {
  extern __shared__ char smem[];
  const int tid = threadIdx.x, lane = tid & 63, wid = tid >> 6;
  const int l31 = lane & 31, l5 = lane >> 5;
  const int rowblk = blockIdx.x >> 1, fh = blockIdx.x & 1;
  const char* w1base = w1g + (size_t)(fh * 32) * 32768;

  // issue w1 chunks 0,1 (land during prologue)
  ISSUE4(0, w1base);
  ISSUE4(32768, w1base + 32768);

  // x rows -> swizzled f32 slab -> owner wave's 32 full-K frags + spike
  bf16x8 xr[32];
  float* xs = (float*)(smem + 65536);
  for (int r = 0; r < 8; ++r) {
    {
      const float* xg = x + (size_t)(rowblk * 256 + r * 32) * D;
#pragma unroll
      for (int it = 0; it < 8; ++it) {
        int idx = it * 512 + tid;
        int rl = idx >> 7, col = (idx & 127) * 4;
        float4 v = *(const float4*)(xg + rl * 512 + col);
        *(float4*)(xs + rl * 512 + (col ^ ((rl & 7) << 2))) = v;
      }
    }
    asm volatile("s_waitcnt vmcnt(0) lgkmcnt(0)" ::: "memory");
    __builtin_amdgcn_s_barrier();
    if (wid == r) {
      bool any = false;
#pragma unroll
      for (int s = 0; s < 32; ++s) {
        int base = s * 16 + l5 * 8;
        int c0 = base ^ ((l31 & 7) << 2);
        int c1 = (base + 4) ^ ((l31 & 7) << 2);
        float4 a4 = *(const float4*)(xs + l31 * 512 + c0);
        float4 b4 = *(const float4*)(xs + l31 * 512 + c1);
        any = any | (fabsf(a4.x) > TH) | (fabsf(a4.y) > TH) | (fabsf(a4.z) > TH) |
              (fabsf(a4.w) > TH) | (fabsf(b4.x) > TH) | (fabsf(b4.y) > TH) |
              (fabsf(b4.z) > TH) | (fabsf(b4.w) > TH);
        bf16x8 t;
        t[0] = f2bf(a4.x); t[1] = f2bf(a4.y); t[2] = f2bf(a4.z); t[3] = f2bf(a4.w);
        t[4] = f2bf(b4.x); t[5] = f2bf(b4.y); t[6] = f2bf(b4.z); t[7] = f2bf(b4.w);
        xr[s] = t;
      }
      unsigned long long bl = __ballot(any);
      if (lane == 0) spikeg[rowblk * 8 + r] = (unsigned)bl | (unsigned)(bl >> 32);
    }
    asm volatile("s_waitcnt lgkmcnt(0)" ::: "memory");
    __builtin_amdgcn_s_barrier();
  }

  // main loop: 32 hk-chunks. counted vmcnt(8) (queue per chunk: bias-loads 4 +
  // h-stores 4 + w1-prefetch 4 -> entry drains w1[ch] exactly).
  char* hbase = hg + (((size_t)(rowblk * 2 + (wid >> 2)) * 64 + fh * 32) * 8192) +
                (wid & 3) * 2048 + l31 * 16 + l5 * 8;
  const float* b1c = b1 + fh * 1024 + l5 * 4;

#pragma unroll 1
  for (int ch = 0; ch < 32; ++ch) {
    asm volatile("s_waitcnt vmcnt(8)" ::: "memory");
    __builtin_amdgcn_s_barrier();
    const char* slot = smem + ((ch & 1) ? 32768 : 0);
    float4 bv0 = *(const float4*)(b1c + ch * 32 + 0);
    float4 bv1 = *(const float4*)(b1c + ch * 32 + 8);
    float4 bv2 = *(const float4*)(b1c + ch * 32 + 16);
    float4 bv3 = *(const float4*)(b1c + ch * 32 + 24);
    f32x16 ha, hb;
#pragma unroll
    for (int j = 0; j < 16; ++j) { ha[j] = 0.f; hb[j] = 0.f; }
    __builtin_amdgcn_s_setprio(1);
#pragma unroll
    for (int s = 0; s < 16; ++s) {
      bf16x8 w0 = *(const bf16x8*)(slot + (2 * s) * 1024 + lane * 16);
      bf16x8 w1f = *(const bf16x8*)(slot + (2 * s + 1) * 1024 + lane * 16);
      ha = MFMA32(w0, xr[2 * s], ha);
      hb = MFMA32(w1f, xr[2 * s + 1], hb);
    }
    __builtin_amdgcn_s_setprio(0);
    // bias + relu + pack -> h global (coalesced 512B per group)
    char* hc = hbase + (size_t)ch * 8192;
    {
      short4 pk;
      pk.x = f2bf(fmaxf(ha[0] + hb[0] + bv0.x, 0.f));
      pk.y = f2bf(fmaxf(ha[1] + hb[1] + bv0.y, 0.f));
      pk.z = f2bf(fmaxf(ha[2] + hb[2] + bv0.z, 0.f));
      pk.w = f2bf(fmaxf(ha[3] + hb[3] + bv0.w, 0.f));
      *(short4*)(hc + 0 * 512) = pk;
      pk.x = f2bf(fmaxf(ha[4] + hb[4] + bv1.x, 0.f));
      pk.y = f2bf(fmaxf(ha[5] + hb[5] + bv1.y, 0.f));
      pk.z = f2bf(fmaxf(ha[6] + hb[6] + bv1.z, 0.f));
      pk.w = f2bf(fmaxf(ha[7] + hb[7] + bv1.w, 0.f));
      *(short4*)(hc + 1 * 512) = pk;
      pk.x = f2bf(fmaxf(ha[8] + hb[8] + bv2.x, 0.f));
      pk.y = f2bf(fmaxf(ha[9] + hb[9] + bv2.y, 0.f));
      pk.z = f2bf(fmaxf(ha[10] + hb[10] + bv2.z, 0.f));
      pk.w = f2bf(fmaxf(ha[11] + hb[11] + bv2.w, 0.f));
      *(short4*)(hc + 2 * 512) = pk;
      pk.x = f2bf(fmaxf(ha[12] + hb[12] + bv3.x, 0.f));
      pk.y = f2bf(fmaxf(ha[13] + hb[13] + bv3.y, 0.f));
      pk.z = f2bf(fmaxf(ha[14] + hb[14] + bv3.z, 0.f));
      pk.w = f2bf(fmaxf(ha[15] + hb[15] + bv3.w, 0.f));
      *(short4*)(hc + 3 * 512) = pk;
    }
    asm volatile("s_waitcnt lgkmcnt(0)" ::: "memory");
    __builtin_amdgcn_s_barrier();  // all reads of this slot done
    if (ch + 2 < 32) ISSUE4((ch & 1) ? 32768 : 0, w1base + (size_t)(ch + 2) * 32768);
  }
}

// ===========================================================================
// UNFUSED PATH, kernel 2: out = spike ? (h*w2 + b2) : 0.
// grid = M/128: block mb owns rows mb*128..+127, all 512 cols.
// LDS: w2 slot0 0..32KB, slot1 32..64KB, h slot0 @65536 (8KB), slot1 @73728.
// ===========================================================================
__global__ __launch_bounds__(512, 2)
void g2_kernel(const float* __restrict__ b2, const char* __restrict__ w2g,
               const char* __restrict__ hg, const unsigned* __restrict__ spikeg,
               float* __restrict__ out) {
  extern __shared__ char smem[];
  const int tid = threadIdx.x, lane = tid & 63, wid = tid >> 6;
  const int l31 = lane & 31, l5 = lane >> 5;
  const int cq = wid & 3, rh = wid >> 2;
  const int mb = blockIdx.x;
  const char* hgm = hg + (size_t)mb * 64 * 8192;

  // prologue: kc0 group (h,w2 = 5 loads) then kc1 group
  ISSUE1(65536, hgm);
  ISSUE4(0, w2g);
  ISSUE1(73728, hgm + 8192);
  ISSUE4(32768, w2g + 32768);

  f32x16 oacc[8];
#pragma unroll
  for (int n = 0; n < 8; ++n)
#pragma unroll
    for (int j = 0; j < 16; ++j) oacc[n][j] = 0.f;

#pragma unroll 1
  for (int kc = 0; kc < 64; ++kc) {
    if (kc < 63) asm volatile("s_waitcnt vmcnt(5)" ::: "memory");
    else         asm volatile("s_waitcnt vmcnt(0)" ::: "memory");
    __builtin_amdgcn_s_barrier();
    const char* hS  = smem + ((kc & 1) ? 73728 : 65536);
    const char* w2S = smem + ((kc & 1) ? 32768 : 0);
    __builtin_amdgcn_s_setprio(1);
#pragma unroll
    for (int ks = 0; ks < 2; ++ks) {
      bf16x8 hA0 = *(const bf16x8*)(hS + (rh * 2 + 0) * 2048 + (2 * ks + l5) * 512 + l31 * 16);
      bf16x8 hA1 = *(const bf16x8*)(hS + (rh * 2 + 1) * 2048 + (2 * ks + l5) * 512 + l31 * 16);
#pragma unroll
      for (int n = 0; n < 4; ++n) {
        bf16x8 wf = *(const bf16x8*)(w2S + ks * 16384 + (cq * 4 + n) * 1024 + lane * 16);
        oacc[n]     = MFMA32(hA0, wf, oacc[n]);
        oacc[4 + n] = MFMA32(hA1, wf, oacc[4 + n]);
      }
    }
    __builtin_amdgcn_s_setprio(0);
    asm volatile("s_waitcnt lgkmcnt(0)" ::: "memory");
    __builtin_amdgcn_s_barrier();
    if (kc + 2 < 64) {
      ISSUE1((kc & 1) ? 73728 : 65536, hgm + (size_t)(kc + 2) * 8192);
      ISSUE4((kc & 1) ? 32768 : 0, w2g + (size_t)(kc + 2) * 32768);
    }
  }

  // epilogue: + b2, spike mask, store (R12-verified C/D mapping)
  unsigned mw0 = spikeg[mb * 4 + rh * 2 + 0];
  unsigned mw1 = spikeg[mb * 4 + rh * 2 + 1];
#pragma unroll
  for (int rfi = 0; rfi < 2; ++rfi) {
    unsigned m = rfi ? mw1 : mw0;
#pragma unroll
    for (int n = 0; n < 4; ++n) {
      int dcol = cq * 128 + n * 32 + l31;
      float bias = b2[dcol];
      f32x16 acc = oacc[rfi * 4 + n];
#pragma unroll
      for (int r = 0; r < 16; ++r) {
        int rbit = (r & 3) + 8 * (r >> 2) + 4 * l5;
        int row = rh * 64 + rfi * 32 + rbit;
        float v = acc[r] + bias;
        out[(size_t)(mb * 128 + row) * D + dcol] = ((m >> rbit) & 1u) ? v : 0.f;
      }
    }
  }
}

// ===========================================================================
// FUSED FALLBACK (verified R12/R17, byte-identical) — used if ws_size too
// small for the 128MB h buffer.
// ===========================================================================
__global__ __launch_bounds__(512, 2)
void ffn_fused(const float* __restrict__ x,
               const float* __restrict__ b1,
               const float* __restrict__ b2,
               const char* __restrict__ w1g,
               const char* __restrict__ w2g,
               float* __restrict__ out) {
  extern __shared__ char smem[];
  const int tid = threadIdx.x;
  const int lane = tid & 63, wid = tid >> 6;
  const int l31 = lane & 31, l5 = lane >> 5;
  const int row0 = blockIdx.x * BM;

  const int p  = wid & 3,  kh = wid >> 2;
  const int cq = wid & 3,  rh = wid >> 2;
  unsigned* tmpspk = (unsigned*)(smem + H2_0);

  if (tid < 4) tmpspk[tid] = 0u;
  ISSUE4(W1A_O, w1g);
  *(float4*)((float*)(smem + B1_O) + tid * 4) = *(const float4*)&b1[tid * 4];

  bf16x8 xr[16];
  for (int r = 0; r < 4; ++r) {
    {
      const float* xg = x + (size_t)(row0 + r * 32) * D;
      float* xs = (float*)(smem + W2A_O);
#pragma unroll
      for (int it = 0; it < 8; ++it) {
        int idx = it * 512 + tid;
        int rl = idx >> 7, col = (idx & 127) * 4;
        float4 v = *(const float4*)(xg + rl * 512 + col);
        *(float4*)(xs + rl * 512 + (col ^ ((rl & 7) << 2))) = v;
      }
    }
    asm volatile("s_waitcnt vmcnt(0) lgkmcnt(0)" ::: "memory");
    __builtin_amdgcn_s_barrier();
    if (p == r) {
      const float* xs = (const float*)(smem + W2A_O);
      bool rowany = false;
#pragma unroll
      for (int s = 0; s < 16; ++s) {
        int base = kh * 256 + s * 16 + l5 * 8;
        int c0 = base ^ ((l31 & 7) << 2);
        int c1 = (base + 4) ^ ((l31 & 7) << 2);
        float4 a4 = *(const float4*)(xs + l31 * 512 + c0);
        float4 b4 = *(const float4*)(xs + l31 * 512 + c1);
        rowany = rowany | (fabsf(a4.x) > TH) | (fabsf(a4.y) > TH) |
                 (fabsf(a4.z) > TH) | (fabsf(a4.w) > TH) | (fabsf(b4.x) > TH) |
                 (fabsf(b4.y) > TH) | (fabsf(b4.z) > TH) | (fabsf(b4.w) > TH);
        bf16x8 t;
        t[0] = f2bf(a4.x); t[1] = f2bf(a4.y); t[2] = f2bf(a4.z); t[3] = f2bf(a4.w);
        t[4] = f2bf(b4.x); t[5] = f2bf(b4.y); t[6] = f2bf(b4.z); t[7] = f2bf(b4.w);
        xr[s] = t;
      }
      unsigned long long bl = __ballot(rowany);
      if (lane == 0) atomicOr(&tmpspk[r], (unsigned)bl | (unsigned)(bl >> 32));
    }
    asm volatile("s_waitcnt lgkmcnt(0)" ::: "memory");
    __builtin_amdgcn_s_barrier();
  }
  const unsigned smv0 = tmpspk[rh * 2 + 0];
  const unsigned smv1 = tmpspk[rh * 2 + 1];
  asm volatile("s_waitcnt vmcnt(0) lgkmcnt(0)" ::: "memory");
  __builtin_amdgcn_s_barrier();

  ISSUE4(W1B_O, w1g + 32768);
  ISSUE4(W2A_O, w2g);

  f32x16 oacc[8];
#pragma unroll
  for (int n = 0; n < 8; ++n)
#pragma unroll
    for (int j = 0; j < 16; ++j) oacc[n][j] = 0.f;

  const float* b1s = (const float*)(smem + B1_O);

#pragma unroll 1
  for (int i = 0; i < NC; ++i) {
    const int sl = i & 1;
    f32x16 hacc;

    if (i < NC - 1) asm volatile("s_waitcnt vmcnt(8)" ::: "memory");
    else            asm volatile("s_waitcnt vmcnt(4)" ::: "memory");

    __builtin_amdgcn_s_setprio(1);
    if (i > 0) {
      const int js = (i - 1) & 1;
      const char* h2r  = smem + (js ? H2_1 : H2_0);
      const char* w2rd = smem + (js ? W2B_O : W2A_O);
#pragma unroll
      for (int ks = 0; ks < 2; ++ks) {
        bf16x8 hA0 = *(const bf16x8*)(h2r + ((2 * ks + l5) * 128 + rh * 64 + l31) * 16);
        bf16x8 hA1 = *(const bf16x8*)(h2r + ((2 * ks + l5) * 128 + rh * 64 + 32 + l31) * 16);
#pragma unroll
        for (int n = 0; n < 4; ++n) {
          bf16x8 wf = *(const bf16x8*)(w2rd + ks * 16384 + (cq * 4 + n) * 1024 + lane * 16);
          oacc[n]     = MFMA32(hA0, wf, oacc[n]);
          oacc[4 + n] = MFMA32(hA1, wf, oacc[4 + n]);
        }
      }
    }
    {
      const char* w1slot = smem + (sl ? W1B_O : W1A_O);
#pragma unroll
      for (int j = 0; j < 16; ++j) hacc[j] = 0.f;
#pragma unroll
      for (int s = 0; s < 16; ++s) {
        bf16x8 wf = *(const bf16x8*)(w1slot + (kh * 16 + s) * 1024 + lane * 16);
        hacc = MFMA32(wf, xr[s], hacc);
      }
    }
    __builtin_amdgcn_s_setprio(0);
    if (kh) {
      u32x4 pk0, pk1;
#pragma unroll
      for (int t = 0; t < 4; ++t) {
        pk0[t] = (unsigned)(unsigned short)f2bf(hacc[2 * t]) |
                 ((unsigned)(unsigned short)f2bf(hacc[2 * t + 1]) << 16);
        pk1[t] = (unsigned)(unsigned short)f2bf(hacc[8 + 2 * t]) |
                 ((unsigned)(unsigned short)f2bf(hacc[8 + 2 * t + 1]) << 16);
      }
      *(u32x4*)(smem + HP_O + p * 2048 + lane * 32) = pk0;
      *(u32x4*)(smem + HP_O + p * 2048 + lane * 32 + 16) = pk1;
    }
    asm volatile("s_waitcnt lgkmcnt(0)" ::: "memory");
    __builtin_amdgcn_s_barrier();

    if (!kh) {
      const char* hp = smem + HP_O + p * 2048;
      u32x4 q0 = *(const u32x4*)(hp + lane * 32);
      u32x4 q1 = *(const u32x4*)(hp + lane * 32 + 16);
#pragma unroll
      for (int t = 0; t < 4; ++t) {
        hacc[2 * t]     += __uint_as_float(q0[t] << 16);
        hacc[2 * t + 1] += __uint_as_float(q0[t] & 0xffff0000u);
        hacc[8 + 2 * t]     += __uint_as_float(q1[t] << 16);
        hacc[8 + 2 * t + 1] += __uint_as_float(q1[t] & 0xffff0000u);
      }
      char* h2w = smem + (sl ? H2_1 : H2_0);
#pragma unroll
      for (int q = 0; q < 4; ++q) {
        float4 bv = *(const float4*)&b1s[i * 32 + q * 8 + l5 * 4];
        short4 pk;
        pk.x = f2bf(fmaxf(hacc[4 * q + 0] + bv.x, 0.f));
        pk.y = f2bf(fmaxf(hacc[4 * q + 1] + bv.y, 0.f));
        pk.z = f2bf(fmaxf(hacc[4 * q + 2] + bv.z, 0.f));
        pk.w = f2bf(fmaxf(hacc[4 * q + 3] + bv.w, 0.f));
        *(short4*)(h2w + q * 2048 + (p * 32 + l31) * 16 + l5 * 8) = pk;
      }
    }
    if (i + 2 < NC) ISSUE4(sl ? W1B_O : W1A_O, w1g + (size_t)(i + 2) * 32768);
    if (i + 1 < NC) ISSUE4(((i + 1) & 1) ? W2B_O : W2A_O,
                           w2g + (size_t)(i + 1) * 32768);
    asm volatile("s_waitcnt lgkmcnt(0)" ::: "memory");
    __builtin_amdgcn_s_barrier();
  }

  asm volatile("s_waitcnt vmcnt(0)" ::: "memory");
  {
    const char* h2r  = smem + H2_1;
    const char* w2rd = smem + W2B_O;
    __builtin_amdgcn_s_setprio(1);
#pragma unroll
    for (int ks = 0; ks < 2; ++ks) {
      bf16x8 hA0 = *(const bf16x8*)(h2r + ((2 * ks + l5) * 128 + rh * 64 + l31) * 16);
      bf16x8 hA1 = *(const bf16x8*)(h2r + ((2 * ks + l5) * 128 + rh * 64 + 32 + l31) * 16);
#pragma unroll
      for (int n = 0; n < 4; ++n) {
        bf16x8 wf = *(const bf16x8*)(w2rd + ks * 16384 + (cq * 4 + n) * 1024 + lane * 16);
        oacc[n]     = MFMA32(hA0, wf, oacc[n]);
        oacc[4 + n] = MFMA32(hA1, wf, oacc[4 + n]);
      }
    }
    __builtin_amdgcn_s_setprio(0);
  }
#pragma unroll
  for (int rfi = 0; rfi < 2; ++rfi) {
    unsigned m = rfi ? smv1 : smv0;
#pragma unroll
    for (int n = 0; n < 4; ++n) {
      int dcol = cq * 128 + n * 32 + l31;
      float bias = b2[dcol];
      f32x16 acc = oacc[rfi * 4 + n];
#pragma unroll
      for (int r = 0; r < 16; ++r) {
        int rbit = (r & 3) + 8 * (r >> 2) + 4 * l5;
        int row = rh * 64 + rfi * 32 + rbit;
        float v = acc[r] + bias;
        out[(size_t)(row0 + row) * D + dcol] = ((m >> rbit) & 1u) ? v : 0.f;
      }
    }
  }
}

extern "C" void kernel_launch(void* const* d_in, const int* in_sizes, int n_in,
                              void* d_out, int out_size, void* d_ws, size_t ws_size,
                              hipStream_t stream) {
  const float* x  = (const float*)d_in[0];
  const float* w1 = (const float*)d_in[1];
  const float* b1 = (const float*)d_in[2];
  const float* w2 = (const float*)d_in[3];
  const float* b2 = (const float*)d_in[4];
  float* out = (float*)d_out;

  short* w1staged = (short*)d_ws;               // 2 MB
  short* w2staged = w1staged + (size_t)D * F;   // 2 MB

  prep_weights<<<1024, 256, 0, stream>>>(w1, w2, w1staged, w2staged);

  int M = out_size / D;  // 32768
  const size_t SPK_OFF = 4ull * 1024 * 1024;
  const size_t H_OFF   = SPK_OFF + 65536;
  const size_t NEED    = H_OFF + (size_t)M * F * 2;  // ~132 MB

  if (ws_size >= NEED) {
    unsigned* spikeg = (unsigned*)((char*)d_ws + SPK_OFF);
    char* hg = (char*)d_ws + H_OFF;
    (void)hipFuncSetAttribute((const void*)g1_kernel,
                              hipFuncAttributeMaxDynamicSharedMemorySize, 131072);
    (void)hipFuncSetAttribute((const void*)g2_kernel,
                              hipFuncAttributeMaxDynamicSharedMemorySize, 81920);
    g1_kernel<<<(M / 256) * 2, 512, 131072, stream>>>(
        x, b1, (const char*)w1staged, hg, spikeg);
    g2_kernel<<<M / 128, 512, 81920, stream>>>(
        b2, (const char*)w2staged, hg, spikeg, out);
  } else {
    (void)hipFuncSetAttribute((const void*)ffn_fused,
                              hipFuncAttributeMaxDynamicSharedMemorySize, LDS_TOTAL);
    ffn_fused<<<M / BM, 512, LDS_TOTAL, stream>>>(
        x, b1, b2, (const char*)w1staged, (const char*)w2staged, out);
  }
}